// Round 3
// baseline (426.487 us; speedup 1.0000x reference)
//
#include <hip/hip_runtime.h>

#define B_TOT   65536
#define DIN     1024
#define NNODES  255
#define NPAD    256
#define DOUT    128
#define BM      64
#define BK      64
#define NKT     (DIN / BK)   // 16 K-tiles

typedef __attribute__((ext_vector_type(8))) _Float16      f16x8;
typedef __attribute__((ext_vector_type(4))) float         f32x4;
typedef __attribute__((ext_vector_type(4))) unsigned short u16x4;
typedef __attribute__((ext_vector_type(8))) unsigned short u16x8;
typedef unsigned short u16;
typedef unsigned int   u32;

__device__ __forceinline__ u16 f2h(float f) {
  _Float16 h = (_Float16)f;
  return __builtin_bit_cast(u16, h);
}
__device__ __forceinline__ float h2f(u16 b) {
  return (float)__builtin_bit_cast(_Float16, b);
}
// packed fp32x2 -> fp16x2 (v_cvt_pkrtz_f16_f32), returned as u32
__device__ __forceinline__ u32 pk2h(float a, float b) {
  return __builtin_bit_cast(u32, __builtin_amdgcn_cvt_pkrtz(a, b));
}

// XOR-swizzled index into a [rows][64] fp16 LDS tile (row stride 64 elems = 128B).
// 16B granule g = col>>3 is xor'ed with row&7 -> conflict-free frag reads, 16B aligned.
__device__ __forceinline__ int swz64(int row, int col) {
  return (row << 6) + ((((col >> 3) ^ row) & 7) << 3) + (col & 7);
}
// Same idea for the [64][256] P/probs tile.
__device__ __forceinline__ int swzP(int row, int col) {
  int g = col >> 3;
  int gs = (g & ~7) | ((g ^ row) & 7);
  return (row << 8) + (gs << 3) + (col & 7);
}

// Transpose W (DIN x NNODES fp32) -> Wt (NPAD x DIN fp16), coalesced both sides.
__global__ void prep_w(const float* __restrict__ Wsp, u16* __restrict__ Wt) {
  __shared__ float t[64][65];
  const int tid = threadIdx.x;
  const int bn = blockIdx.x * 64;   // node tile (4 tiles)
  const int bk = blockIdx.y * 64;   // k tile    (16 tiles)
  {
    int n = tid & 63, kr0 = tid >> 6;
    #pragma unroll
    for (int i = 0; i < 16; ++i) {
      int k = kr0 + i * 4;
      int node = bn + n;
      t[k][n] = (node < NNODES) ? Wsp[(size_t)(bk + k) * NNODES + node] : 0.0f;
    }
  }
  __syncthreads();
  {
    int k = tid & 63, nr0 = tid >> 6;
    #pragma unroll
    for (int i = 0; i < 16; ++i) {
      int node = nr0 + i * 4;
      Wt[(size_t)(bn + node) * DIN + bk + k] = f2h(t[k][node]);
    }
  }
}

__global__ void prep_leaf(const float* __restrict__ leaf, u16* __restrict__ lT) {
  int t = blockIdx.x * 256 + threadIdx.x;       // 32768 = 128 j x 256 leaves
  int j = t & 127, l = t >> 7;
  lT[j * NPAD + l] = f2h(leaf[l * DOUT + j]);   // coalesced read over j
}

__global__ __launch_bounds__(256, 3) void fused_sdt(
    const float* __restrict__ x, const float* __restrict__ bsp,
    const u16* __restrict__ Wt, const u16* __restrict__ lT,
    float* __restrict__ out, float* __restrict__ regp)
{
  // LDS union (49184 B total, 3 blocks/CU):
  //   phase 1: xs [0,8192) + ws [8192,40960)
  //   phase 2/3: PB [0,32768)  (P fp16, then probs fp16 in place)
  //   phase 4: PB + lTs [32768,49152)
  //   red at 49152
  __shared__ char smem[49184] __attribute__((aligned(16)));
  u16* xs  = (u16*)smem;
  u16* ws  = (u16*)(smem + 8192);
  u16* PB  = (u16*)smem;
  u16* lTs = (u16*)(smem + 32768);
  float* red = (float*)(smem + 49152);

  const int tid  = threadIdx.x;
  const int lane = tid & 63;
  const int w    = tid >> 6;
  const int l15  = lane & 15;
  const int quad = lane >> 4;
  const int blk  = blockIdx.x;

  const float* xg = x + (size_t)blk * BM * DIN;

  // Per-thread staging coordinates (fixed across K-tiles):
  //   x: 4 x float4; element (xrow, xkg*4 + k0)
  //   W: 8 x u16x8;  element (wn, wkg*8 + k0)
  const int xrow[4] = { (0*256 + tid) >> 4, (1*256 + tid) >> 4,
                        (2*256 + tid) >> 4, (3*256 + tid) >> 4 };
  const int xkg = tid & 15;
  const int wn[8] = { (0*256 + tid) >> 3, (1*256 + tid) >> 3, (2*256 + tid) >> 3,
                      (3*256 + tid) >> 3, (4*256 + tid) >> 3, (5*256 + tid) >> 3,
                      (6*256 + tid) >> 3, (7*256 + tid) >> 3 };
  const int wkg = tid & 7;

  f32x4 acc[4][4];
  #pragma unroll
  for (int mt = 0; mt < 4; ++mt)
    #pragma unroll
    for (int nt = 0; nt < 4; ++nt) {
      f32x4 z = {0.0f, 0.0f, 0.0f, 0.0f};
      acc[mt][nt] = z;
    }

  float4 xp[4];
  u16x8  wp[8];

  // preload tile 0 into regs
  #pragma unroll
  for (int i = 0; i < 4; ++i)
    xp[i] = *(const float4*)(xg + xrow[i] * DIN + xkg * 4);
  #pragma unroll
  for (int i = 0; i < 8; ++i)
    wp[i] = *(const u16x8*)(Wt + wn[i] * DIN + wkg * 8);
  // write tile 0 to LDS
  #pragma unroll
  for (int i = 0; i < 4; ++i) {
    u32 lo = pk2h(xp[i].x, xp[i].y);
    u32 hi = pk2h(xp[i].z, xp[i].w);
    u16x4 h;
    h.x = lo & 0xffff; h.y = lo >> 16;
    h.z = hi & 0xffff; h.w = hi >> 16;
    *(u16x4*)&xs[swz64(xrow[i], xkg * 4)] = h;
  }
  #pragma unroll
  for (int i = 0; i < 8; ++i)
    *(u16x8*)&ws[swz64(wn[i], wkg * 8)] = wp[i];

  // ---------------- GEMM1: z = x @ W  (M=64, N=256, K=1024) ----------------
  for (int kc = 0; kc < NKT; ++kc) {
    __syncthreads();                 // publish tile kc
    // issue prefetch loads for tile kc+1 NOW: they get the whole MFMA phase
    // (~2K cyc) of cover before the next barrier's vmcnt drain.
    if (kc + 1 < NKT) {
      const int k1 = (kc + 1) * BK;
      #pragma unroll
      for (int i = 0; i < 4; ++i)
        xp[i] = *(const float4*)(xg + xrow[i] * DIN + k1 + xkg * 4);
      #pragma unroll
      for (int i = 0; i < 8; ++i)
        wp[i] = *(const u16x8*)(Wt + wn[i] * DIN + k1 + wkg * 8);
    }
    #pragma unroll
    for (int ks = 0; ks < 2; ++ks) {
      const int kk = ks * 32 + quad * 8;
      f16x8 A[4], Bf[4];
      #pragma unroll
      for (int mt = 0; mt < 4; ++mt)
        A[mt] = *(const f16x8*)&xs[swz64(mt * 16 + l15, kk)];
      #pragma unroll
      for (int nt = 0; nt < 4; ++nt)
        Bf[nt] = *(const f16x8*)&ws[swz64(w * 64 + nt * 16 + l15, kk)];
      #pragma unroll
      for (int mt = 0; mt < 4; ++mt)
        #pragma unroll
        for (int nt = 0; nt < 4; ++nt)
          acc[mt][nt] = __builtin_amdgcn_mfma_f32_16x16x32_f16(
              A[mt], Bf[nt], acc[mt][nt], 0, 0, 0);
    }
    __syncthreads();                 // all reads of tile kc done
    if (kc + 1 < NKT) {
      #pragma unroll
      for (int i = 0; i < 4; ++i) {
        u32 lo = pk2h(xp[i].x, xp[i].y);
        u32 hi = pk2h(xp[i].z, xp[i].w);
        u16x4 h;
        h.x = lo & 0xffff; h.y = lo >> 16;
        h.z = hi & 0xffff; h.w = hi >> 16;
        *(u16x4*)&xs[swz64(xrow[i], xkg * 4)] = h;
      }
      #pragma unroll
      for (int i = 0; i < 8; ++i)
        *(u16x8*)&ws[swz64(wn[i], wkg * 8)] = wp[i];
    }
  }
  __syncthreads();   // staging buffers dead; PB may now alias them

  // ------------- epilogue 1: sigmoid, reg partial, P -> LDS fp16 -------------
  float rsum = 0.0f;
  float bv[4];
  #pragma unroll
  for (int nt = 0; nt < 4; ++nt) {
    int c = w * 64 + nt * 16 + l15;
    bv[nt] = (c < NNODES) ? bsp[c] : 0.0f;
  }
  #pragma unroll
  for (int mt = 0; mt < 4; ++mt) {
    #pragma unroll
    for (int nt = 0; nt < 4; ++nt) {
      int c = w * 64 + nt * 16 + l15;
      #pragma unroll
      for (int r = 0; r < 4; ++r) {
        int row = mt * 16 + quad * 4 + r;
        float z = acc[mt][nt][r] + bv[nt];
        float e = __expf(-z);
        float p = __builtin_amdgcn_rcpf(1.0f + e);
        PB[swzP(row, c)] = f2h(p);
        if (c < NNODES) {
          float v = fmaxf(p * (1.0f - p), 1e-5f);
          int d = 31 - __clz(c + 1);                       // depth of node c
          float wgt = __builtin_bit_cast(float, (u32)(127 - d) << 23);  // 2^-d
          rsum += wgt * __logf(v);
        }
      }
    }
  }
  #pragma unroll
  for (int off = 32; off > 0; off >>= 1) rsum += __shfl_down(rsum, off, 64);
  if (lane == 0) red[w] = rsum;
  __syncthreads();   // also publishes PB to all waves
  if (tid == 0) {
    float s = (red[0] + red[1] + red[2] + red[3]) * (-0.5f / 65536.0f);
    atomicAdd(regp, s);
  }

  // ------------- tree: leaf path products, overwrite PB in place -------------
  // wave w owns rows [16w,16w+16); per row, lane l computes leaves 4l..4l+3.
  // DS ops are in-order per wave: all reads of row issue before the write.
  for (int rr = 0; rr < 16; ++rr) {
    int row = (w << 4) + rr;
    float prod = 1.0f;
    #pragma unroll
    for (int d = 0; d < 6; ++d) {
      int node = (1 << d) - 1 + (lane >> (6 - d));
      float pv = h2f(PB[swzP(row, node)]);
      prod *= ((lane >> (5 - d)) & 1) ? pv : (1.0f - pv);
    }
    float p6  = h2f(PB[swzP(row, 63 + lane)]);
    float p7a = h2f(PB[swzP(row, 127 + 2 * lane)]);
    float p7b = h2f(PB[swzP(row, 128 + 2 * lane)]);
    float a0 = prod * (1.0f - p6), a1 = prod * p6;
    u16x4 o;
    o.x = f2h(a0 * (1.0f - p7a));
    o.y = f2h(a0 * p7a);
    o.z = f2h(a1 * (1.0f - p7b));
    o.w = f2h(a1 * p7b);
    *(u16x4*)&PB[swzP(row, 4 * lane)] = o;
  }

  // ---------------- GEMM2: out = probs @ leaf  (64 x 128, K=256) ----------------
  f32x4 acc2[4][2];
  #pragma unroll
  for (int mt = 0; mt < 4; ++mt)
    #pragma unroll
    for (int nt = 0; nt < 2; ++nt) {
      f32x4 z = {0.0f, 0.0f, 0.0f, 0.0f};
      acc2[mt][nt] = z;
    }
  for (int kc = 0; kc < 4; ++kc) {
    __syncthreads();
    #pragma unroll
    for (int i = 0; i < 4; ++i) {
      int idx = i * 256 + tid;
      int j = idx >> 3, kg = idx & 7;
      u16x8 v = *(const u16x8*)(lT + j * NPAD + kc * 64 + kg * 8);
      *(u16x8*)&lTs[swz64(j, kg * 8)] = v;
    }
    __syncthreads();
    #pragma unroll
    for (int ks = 0; ks < 2; ++ks) {
      f16x8 Af[4], Bf2[2];
      #pragma unroll
      for (int mt = 0; mt < 4; ++mt)
        Af[mt] = *(const f16x8*)&PB[swzP(mt * 16 + l15, kc * 64 + ks * 32 + quad * 8)];
      #pragma unroll
      for (int nt = 0; nt < 2; ++nt)
        Bf2[nt] = *(const f16x8*)&lTs[swz64(w * 32 + nt * 16 + l15, ks * 32 + quad * 8)];
      #pragma unroll
      for (int mt = 0; mt < 4; ++mt)
        #pragma unroll
        for (int nt = 0; nt < 2; ++nt)
          acc2[mt][nt] = __builtin_amdgcn_mfma_f32_16x16x32_f16(
              Af[mt], Bf2[nt], acc2[mt][nt], 0, 0, 0);
    }
  }
  #pragma unroll
  for (int mt = 0; mt < 4; ++mt)
    #pragma unroll
    for (int nt = 0; nt < 2; ++nt)
      #pragma unroll
      for (int r = 0; r < 4; ++r) {
        int row = mt * 16 + quad * 4 + r;
        int col = w * 32 + nt * 16 + l15;
        out[(size_t)(blk * BM + row) * DOUT + col] = acc2[mt][nt][r];
      }
}

extern "C" void kernel_launch(void* const* d_in, const int* in_sizes, int n_in,
                              void* d_out, int out_size, void* d_ws, size_t ws_size,
                              hipStream_t stream) {
  (void)in_sizes; (void)n_in; (void)out_size; (void)ws_size;
  const float* x    = (const float*)d_in[0];
  const float* Wsp  = (const float*)d_in[1];
  const float* bsp  = (const float*)d_in[2];
  const float* leaf = (const float*)d_in[3];
  float* out  = (float*)d_out;
  float* regp = out + (size_t)B_TOT * DOUT;

  u16* Wt = (u16*)d_ws;                 // [256][1024] fp16 = 512 KB
  u16* lT = Wt + NPAD * DIN;            // [128][256]  fp16 = 64 KB

  (void)hipMemsetAsync(regp, 0, sizeof(float), stream);
  prep_w<<<dim3(4, 16), 256, 0, stream>>>(Wsp, Wt);
  prep_leaf<<<(NPAD * DOUT) / 256, 256, 0, stream>>>(leaf, lT);
  fused_sdt<<<B_TOT / BM, 256, 0, stream>>>(x, bsp, Wt, lT, out, regp);
}

// Round 4
// 409.119 us; speedup vs baseline: 1.0425x; 1.0425x over previous
//
#include <hip/hip_runtime.h>

#define B_TOT   65536
#define DIN     1024
#define NNODES  255
#define NPAD    256
#define DOUT    128
#define BM      64
#define BK      64
#define NKT     (DIN / BK)   // 16 K-tiles

typedef __attribute__((ext_vector_type(8))) _Float16      f16x8;
typedef __attribute__((ext_vector_type(4))) float         f32x4;
typedef __attribute__((ext_vector_type(4))) unsigned short u16x4;
typedef __attribute__((ext_vector_type(8))) unsigned short u16x8;
typedef unsigned short u16;
typedef unsigned int   u32;

__device__ __forceinline__ u16 f2h(float f) {
  _Float16 h = (_Float16)f;
  return __builtin_bit_cast(u16, h);
}
__device__ __forceinline__ float h2f(u16 b) {
  return (float)__builtin_bit_cast(_Float16, b);
}
// packed fp32x2 -> fp16x2 (v_cvt_pkrtz_f16_f32), returned as u32
__device__ __forceinline__ u32 pk2h(float a, float b) {
  return __builtin_bit_cast(u32, __builtin_amdgcn_cvt_pkrtz(a, b));
}
// async 16B global->LDS DMA; LDS dest is wave-uniform base + lane*16
__device__ __forceinline__ void cp16_g2s(const u16* g, u16* l) {
  __builtin_amdgcn_global_load_lds(
      (const __attribute__((address_space(1))) unsigned int*)g,
      (__attribute__((address_space(3))) unsigned int*)l, 16, 0, 0);
}

// XOR-swizzled index into a [rows][64] fp16 tile (row stride 64 elems = 128B).
// 16B granule g = col>>3 xor'ed with row&7 -> conflict-free frag reads, 16B aligned.
__device__ __forceinline__ int swz64(int row, int col) {
  return (row << 6) + ((((col >> 3) ^ row) & 7) << 3) + (col & 7);
}
// Same idea for the [64][256] P/probs tile.
__device__ __forceinline__ int swzP(int row, int col) {
  int g = col >> 3;
  int gs = (g & ~7) | ((g ^ row) & 7);
  return (row << 8) + (gs << 3) + (col & 7);
}

// Transpose W (DIN x NNODES fp32) -> WtT, PRE-TILED + PRE-SWIZZLED:
// elem offset = kc*16384 + swz64(node, k&63).  A linear 32KB copy of tile kc
// then lands in LDS already in the swizzled layout the MFMA frag reads expect.
__global__ void prep_w(const float* __restrict__ Wsp, u16* __restrict__ WtT) {
  __shared__ float t[64][65];
  const int tid = threadIdx.x;
  const int bn = blockIdx.x * 64;   // node tile (4 tiles)
  const int kc = blockIdx.y;        // k tile    (16 tiles)
  const int bk = kc * 64;
  {
    int n = tid & 63, kr0 = tid >> 6;
    #pragma unroll
    for (int i = 0; i < 16; ++i) {
      int k = kr0 + i * 4;
      int node = bn + n;
      t[k][n] = (node < NNODES) ? Wsp[(size_t)(bk + k) * NNODES + node] : 0.0f;
    }
  }
  __syncthreads();
  {
    int k = tid & 63, nr0 = tid >> 6;
    #pragma unroll
    for (int i = 0; i < 16; ++i) {
      int node = nr0 + i * 4;
      WtT[kc * (NPAD * BK) + swz64(bn + node, k)] = f2h(t[k][node]);
    }
  }
}

__global__ void prep_leaf(const float* __restrict__ leaf, u16* __restrict__ lT) {
  int t = blockIdx.x * 256 + threadIdx.x;       // 32768 = 128 j x 256 leaves
  int j = t & 127, l = t >> 7;
  lT[j * NPAD + l] = f2h(leaf[l * DOUT + j]);   // coalesced read over j
}

__global__ __launch_bounds__(256, 3) void fused_sdt(
    const float* __restrict__ x, const float* __restrict__ bsp,
    const u16* __restrict__ WtT, const u16* __restrict__ lT,
    float* __restrict__ out, float* __restrict__ regp)
{
  // LDS (40960 B):
  //   phase 1: xs [0,8192) + ws [8192,40960)
  //   phase 2/3/4: PB [0,32768) (P fp16, then probs fp16 in place);
  //                red at [32768,32800) (staging region is dead by then)
  __shared__ char smem[40960] __attribute__((aligned(16)));
  u16* xs  = (u16*)smem;
  u16* ws  = (u16*)(smem + 8192);
  u16* PB  = (u16*)smem;
  float* red = (float*)(smem + 32768);

  const int tid  = threadIdx.x;
  const int lane = tid & 63;
  const int w    = tid >> 6;
  const int l15  = lane & 15;
  const int quad = lane >> 4;
  const int blk  = blockIdx.x;

  const float* xg = x + (size_t)blk * BM * DIN;

  f32x4 acc[4][4];
  #pragma unroll
  for (int mt = 0; mt < 4; ++mt)
    #pragma unroll
    for (int nt = 0; nt < 4; ++nt) {
      f32x4 z = {0.0f, 0.0f, 0.0f, 0.0f};
      acc[mt][nt] = z;
    }

  // ---------------- GEMM1: z = x @ W  (M=64, N=256, K=1024) ----------------
  for (int kc = 0; kc < NKT; ++kc) {
    const int k0 = kc * BK;
    __syncthreads();                       // reads of tile kc-1 done
    // W tile: 32KB linear DMA (pre-swizzled in global) - no VGPRs, no ds_write
    {
      const u16* wtile = WtT + kc * (NPAD * BK);
      #pragma unroll
      for (int i = 0; i < 8; ++i) {
        int chunk = w * 8 + i;             // 32 x 1KB chunks
        cp16_g2s(wtile + chunk * 512 + lane * 8, ws + chunk * 512);
      }
    }
    // x tile: 64 rows x 64 k, fp32 -> fp16 via VGPR (needs convert)
    #pragma unroll
    for (int i = 0; i < 4; ++i) {
      int idx = i * 256 + tid;
      int row = idx >> 4, kg = idx & 15;
      float4 v = *(const float4*)(xg + row * DIN + k0 + kg * 4);
      u32 lo = pk2h(v.x, v.y);
      u32 hi = pk2h(v.z, v.w);
      u16x4 h;
      h.x = lo & 0xffff; h.y = lo >> 16;
      h.z = hi & 0xffff; h.w = hi >> 16;
      *(u16x4*)&xs[swz64(row, kg * 4)] = h;
    }
    __syncthreads();                       // drains DMA (vmcnt) + ds_writes
    #pragma unroll
    for (int ks = 0; ks < 2; ++ks) {
      const int kk = ks * 32 + quad * 8;
      f16x8 A[4], Bf[4];
      #pragma unroll
      for (int mt = 0; mt < 4; ++mt)
        A[mt] = *(const f16x8*)&xs[swz64(mt * 16 + l15, kk)];
      #pragma unroll
      for (int nt = 0; nt < 4; ++nt)
        Bf[nt] = *(const f16x8*)&ws[swz64(w * 64 + nt * 16 + l15, kk)];
      #pragma unroll
      for (int mt = 0; mt < 4; ++mt)
        #pragma unroll
        for (int nt = 0; nt < 4; ++nt)
          acc[mt][nt] = __builtin_amdgcn_mfma_f32_16x16x32_f16(
              A[mt], Bf[nt], acc[mt][nt], 0, 0, 0);
    }
  }
  __syncthreads();   // staging buffers dead; PB may now alias them

  // ------------- epilogue 1: sigmoid, reg partial, P -> LDS fp16 -------------
  float rsum = 0.0f;
  float bv[4];
  #pragma unroll
  for (int nt = 0; nt < 4; ++nt) {
    int c = w * 64 + nt * 16 + l15;
    bv[nt] = (c < NNODES) ? bsp[c] : 0.0f;
  }
  #pragma unroll
  for (int mt = 0; mt < 4; ++mt) {
    #pragma unroll
    for (int nt = 0; nt < 4; ++nt) {
      int c = w * 64 + nt * 16 + l15;
      #pragma unroll
      for (int r = 0; r < 4; ++r) {
        int row = mt * 16 + quad * 4 + r;
        float z = acc[mt][nt][r] + bv[nt];
        float e = __expf(-z);
        float p = __builtin_amdgcn_rcpf(1.0f + e);
        PB[swzP(row, c)] = f2h(p);
        if (c < NNODES) {
          float v = fmaxf(p * (1.0f - p), 1e-5f);
          int d = 31 - __clz(c + 1);                       // depth of node c
          float wgt = __builtin_bit_cast(float, (u32)(127 - d) << 23);  // 2^-d
          rsum += wgt * __logf(v);
        }
      }
    }
  }
  #pragma unroll
  for (int off = 32; off > 0; off >>= 1) rsum += __shfl_down(rsum, off, 64);
  if (lane == 0) red[w] = rsum;
  __syncthreads();   // publishes PB to all waves + red to tid 0
  if (tid == 0) {
    float s = (red[0] + red[1] + red[2] + red[3]) * (-0.5f / 65536.0f);
    atomicAdd(regp, s);
  }

  // ------------- tree: leaf path products, overwrite PB in place -------------
  // wave w owns rows [16w,16w+16); per row, lane l computes leaves 4l..4l+3.
  // DS ops are in-order per wave: all reads of row issue before the write.
  for (int rr = 0; rr < 16; ++rr) {
    int row = (w << 4) + rr;
    float prod = 1.0f;
    #pragma unroll
    for (int d = 0; d < 6; ++d) {
      int node = (1 << d) - 1 + (lane >> (6 - d));
      float pv = h2f(PB[swzP(row, node)]);
      prod *= ((lane >> (5 - d)) & 1) ? pv : (1.0f - pv);
    }
    float p6  = h2f(PB[swzP(row, 63 + lane)]);
    float p7a = h2f(PB[swzP(row, 127 + 2 * lane)]);
    float p7b = h2f(PB[swzP(row, 128 + 2 * lane)]);
    float a0 = prod * (1.0f - p6), a1 = prod * p6;
    u16x4 o;
    o.x = f2h(a0 * (1.0f - p7a));
    o.y = f2h(a0 * p7a);
    o.z = f2h(a1 * (1.0f - p7b));
    o.w = f2h(a1 * p7b);
    *(u16x4*)&PB[swzP(row, 4 * lane)] = o;
  }
  __syncthreads();   // GEMM2 A-frags read rows written by other waves

  // -------- GEMM2: out = probs @ leaf  (64 x 128, K=256), barrier-free ------
  // B frags come straight from global lT (64 KB, L2-resident across blocks).
  f32x4 acc2[4][2];
  #pragma unroll
  for (int mt = 0; mt < 4; ++mt)
    #pragma unroll
    for (int nt = 0; nt < 2; ++nt) {
      f32x4 z = {0.0f, 0.0f, 0.0f, 0.0f};
      acc2[mt][nt] = z;
    }
  for (int kc = 0; kc < 4; ++kc) {
    #pragma unroll
    for (int ks = 0; ks < 2; ++ks) {
      const int kk = kc * 64 + ks * 32 + quad * 8;
      f16x8 Af[4], Bf2[2];
      #pragma unroll
      for (int nt = 0; nt < 2; ++nt)
        Bf2[nt] = *(const f16x8*)&lT[(w * 32 + nt * 16 + l15) * NPAD + kk];
      #pragma unroll
      for (int mt = 0; mt < 4; ++mt)
        Af[mt] = *(const f16x8*)&PB[swzP(mt * 16 + l15, kk)];
      #pragma unroll
      for (int mt = 0; mt < 4; ++mt)
        #pragma unroll
        for (int nt = 0; nt < 2; ++nt)
          acc2[mt][nt] = __builtin_amdgcn_mfma_f32_16x16x32_f16(
              Af[mt], Bf2[nt], acc2[mt][nt], 0, 0, 0);
    }
  }
  #pragma unroll
  for (int mt = 0; mt < 4; ++mt)
    #pragma unroll
    for (int nt = 0; nt < 2; ++nt)
      #pragma unroll
      for (int r = 0; r < 4; ++r) {
        int row = mt * 16 + quad * 4 + r;
        int col = w * 32 + nt * 16 + l15;
        out[(size_t)(blk * BM + row) * DOUT + col] = acc2[mt][nt][r];
      }
}

extern "C" void kernel_launch(void* const* d_in, const int* in_sizes, int n_in,
                              void* d_out, int out_size, void* d_ws, size_t ws_size,
                              hipStream_t stream) {
  (void)in_sizes; (void)n_in; (void)out_size; (void)ws_size;
  const float* x    = (const float*)d_in[0];
  const float* Wsp  = (const float*)d_in[1];
  const float* bsp  = (const float*)d_in[2];
  const float* leaf = (const float*)d_in[3];
  float* out  = (float*)d_out;
  float* regp = out + (size_t)B_TOT * DOUT;

  u16* WtT = (u16*)d_ws;                // [16][16384] fp16 = 512 KB (tiled+swizzled)
  u16* lT  = WtT + NPAD * DIN;          // [128][256]  fp16 = 64 KB

  (void)hipMemsetAsync(regp, 0, sizeof(float), stream);
  prep_w<<<dim3(4, 16), 256, 0, stream>>>(Wsp, WtT);
  prep_leaf<<<(NPAD * DOUT) / 256, 256, 0, stream>>>(leaf, lT);
  fused_sdt<<<B_TOT / BM, 256, 0, stream>>>(x, bsp, WtT, lT, out, regp);
}